// Round 8
// baseline (532.305 us; speedup 1.0000x reference)
//
#include <hip/hip_runtime.h>
#include <hip/hip_fp16.h>
#include <stdint.h>

#define N_USERS   200000
#define N_ITEMS   100000
#define N_NODES   300000
#define EMBED_DIM 64
#define N_EDGES   5000000
#define BATCH     4096

// ---- two-level partition geometry ----
#define ROWS_PER_BUCKET 512
#define PART_K 586                         // ceil(300000/512) buckets
#define PART_B 1024                        // partition blocks
#define CHUNK  4884                        // div by 4; 1024*4884 >= 5M; all blocks get 4|count
#define PART_L (PART_K * PART_B)           // 600064
#define SCAN_T 1024
#define SCAN_NB (PART_L / SCAN_T)          // 586 exactly (tile == bucket)

#define VAL_SCALE 81920.0f                 // maps [0,0.1) -> [0,8192)
#define VAL_INV   (1.0f / 81920.0f)
#define FIN_CAP   10240                    // LDS staging capacity (bucket mean 8533, sd 92)

#define CONV_BLOCKS ((N_NODES * 8 + 1023) / 1024)   // 2344

// fp8 storage scale (R3/R4 notes): scaled values sit in e4m3 normal range.
// fp8 ONLY on the two 5M-gather tables (x0, E1). E1's direct read in the
// combine is RECOMPUTED from x0 gathers inside final_kernel (R5 mechanism).
// R6 lesson: no conditional epilogues in the spmm loop (allocator spills).
#define EMB_SCALE 1024.0f
#define EMB_INV   (1.0f / 1024.0f)

typedef float f32x2 __attribute__((ext_vector_type(2)));

// XCD-grouping permutation of run order within a bucket (bijection on [0,1024))
__device__ __forceinline__ int swz(int b)     { return ((b & 7) << 7) | (b >> 3); }

// ---------------------------------------------------------------------------
// Wave-level scans: 64-lane shfl_up inclusive scan; block scans with only
// 2 barriers (replaces 20-barrier Hillis-Steele — R7 theory: chain is
// launch/barrier-bound, not traffic-bound).
// ---------------------------------------------------------------------------
__device__ __forceinline__ int wscan_incl(int x) {
    #pragma unroll
    for (int d = 1; d < 64; d <<= 1) {
        int t = __shfl_up(x, d);
        if ((int)(threadIdx.x & 63) >= d) x += t;
    }
    return x;
}

// 1024-thread block inclusive scan; ws = LDS int[16]; ws[15] = block total.
__device__ __forceinline__ int bscan1024(int v, int* ws) {
    int tid = threadIdx.x, lane = tid & 63, wv = tid >> 6;
    int x = wscan_incl(v);
    if (lane == 63) ws[wv] = x;
    __syncthreads();
    if (tid < 16) {
        int s = ws[tid];
        #pragma unroll
        for (int d = 1; d < 16; d <<= 1) {
            int t = __shfl_up(s, d, 16);
            if (tid >= d) s += t;
        }
        ws[tid] = s;
    }
    __syncthreads();
    return x + (wv ? ws[wv - 1] : 0);
}

// 512-thread block inclusive scan; ws = LDS int[8]; ws[7] = block total.
__device__ __forceinline__ int bscan512(int v, int* ws) {
    int tid = threadIdx.x, lane = tid & 63, wv = tid >> 6;
    int x = wscan_incl(v);
    if (lane == 63) ws[wv] = x;
    __syncthreads();
    if (tid < 8) {
        int s = ws[tid];
        #pragma unroll
        for (int d = 1; d < 8; d <<= 1) {
            int t = __shfl_up(s, d, 8);
            if (tid >= d) s += t;
        }
        ws[tid] = s;
    }
    __syncthreads();
    return x + (wv ? ws[wv - 1] : 0);
}

// ---------------------------------------------------------------------------
// Fused: part_count histogram (blocks [0,PART_B)) + fp32->fp8 convert
// (blocks [PART_B, PART_B+CONV_BLOCKS)) + scan-state zeroing (last block).
// Independent work, one launch instead of two (+state init free).
// ---------------------------------------------------------------------------
__global__ __launch_bounds__(1024)
void pc_conv(const int* __restrict__ rows, int* __restrict__ hist,
             const float* __restrict__ ue, const float* __restrict__ ie,
             uint2* __restrict__ xf8,
             unsigned long long* __restrict__ lb_state, int* __restrict__ ticket) {
    int bx = blockIdx.x;
    int tid = threadIdx.x;
    if (bx < PART_B) {
        __shared__ int h[PART_K];
        for (int i = tid; i < PART_K; i += 1024) h[i] = 0;
        __syncthreads();
        int beg = bx * CHUNK;
        int end = min(beg + CHUNK, N_EDGES);
        for (int i = beg + tid * 4; i < end; i += 4096) {
            int4 r4 = *(const int4*)(rows + i);
            atomicAdd(&h[r4.x >> 9], 1);
            atomicAdd(&h[r4.y >> 9], 1);
            atomicAdd(&h[r4.z >> 9], 1);
            atomicAdd(&h[r4.w >> 9], 1);
        }
        __syncthreads();
        for (int i = tid; i < PART_K; i += 1024)
            hist[bx * PART_K + i] = h[i];
        return;
    }
    if (bx < PART_B + CONV_BLOCKS) {
        int t = (bx - PART_B) * 1024 + tid;
        if (t >= N_NODES * 8) return;
        int flat = t * 8;
        int row = flat >> 6;
        int off = flat & 63;
        const float* src = (row < N_USERS) ? (ue + (size_t)row * 64 + off)
                                           : (ie + (size_t)(row - N_USERS) * 64 + off);
        float4 a = ((const float4*)src)[0];
        float4 b = ((const float4*)src)[1];
        int lo = __builtin_amdgcn_cvt_pk_fp8_f32(a.x * EMB_SCALE, a.y * EMB_SCALE, 0, 0);
        lo     = __builtin_amdgcn_cvt_pk_fp8_f32(a.z * EMB_SCALE, a.w * EMB_SCALE, lo, 1);
        int hi = __builtin_amdgcn_cvt_pk_fp8_f32(b.x * EMB_SCALE, b.y * EMB_SCALE, 0, 0);
        hi     = __builtin_amdgcn_cvt_pk_fp8_f32(b.z * EMB_SCALE, b.w * EMB_SCALE, hi, 1);
        xf8[t] = make_uint2((unsigned int)lo, (unsigned int)hi);
        return;
    }
    // last block: zero decoupled-lookback state (re-zeroed on every graph replay)
    for (int i = tid; i < SCAN_NB; i += 1024) lb_state[i] = 0ULL;
    if (tid == 0) ticket[0] = 0;
}

// ---------------------------------------------------------------------------
// Single-pass scan over the 600K logical sequence via decoupled lookback.
// Tile bid == bucket bid (SCAN_T == PART_B). Dynamic ranking via atomic
// ticket guarantees progress (lower ranks started earlier). Cross-XCD
// visibility via device-scope (__HIP_MEMORY_SCOPE_AGENT) 64-bit atomics;
// state packs {status:32 | value:32}, status 0=invalid 1=aggregate 2=prefix.
// Replaces scan_partial + scan_addoff (one launch saved, no local_scan
// round-trip, no redundant per-block 586-scan).
// ---------------------------------------------------------------------------
__global__ __launch_bounds__(1024)
void scan_lookback(const int* __restrict__ hist,
                   unsigned long long* __restrict__ state,
                   int* __restrict__ ticket,
                   int* __restrict__ sofs,
                   int* __restrict__ row_ptr) {
    __shared__ int ws[16];
    __shared__ int sh_bid;
    __shared__ int sh_base;
    int tid = threadIdx.x;
    if (tid == 0) sh_bid = atomicAdd(ticket, 1);
    __syncthreads();
    int bid = sh_bid;
    int p = tid;
    int b = ((p & 127) << 3) | (p >> 7);     // inverse swizzle
    int v = hist[b * PART_K + bid];
    int incl = bscan1024(v, ws);
    int total = ws[15];
    if (tid == 0) {
        if (bid == 0) {
            __hip_atomic_store(&state[0], (2ULL << 32) | (unsigned int)total,
                               __ATOMIC_RELEASE, __HIP_MEMORY_SCOPE_AGENT);
            sh_base = 0;
        } else {
            __hip_atomic_store(&state[bid], (1ULL << 32) | (unsigned int)total,
                               __ATOMIC_RELEASE, __HIP_MEMORY_SCOPE_AGENT);
            unsigned int run = 0;
            int j = bid - 1;
            while (true) {
                unsigned long long s = __hip_atomic_load(&state[j],
                                        __ATOMIC_ACQUIRE, __HIP_MEMORY_SCOPE_AGENT);
                unsigned int st = (unsigned int)(s >> 32);
                if (st == 0) continue;               // predecessor not published yet
                run += (unsigned int)s;
                if (st == 2) break;                  // hit a full prefix
                --j;
            }
            __hip_atomic_store(&state[bid], (2ULL << 32) | (unsigned int)(run + (unsigned int)total),
                               __ATOMIC_RELEASE, __HIP_MEMORY_SCOPE_AGENT);
            sh_base = (int)run;
        }
    }
    __syncthreads();
    int gid = bid * SCAN_T + tid;
    sofs[gid] = sh_base + incl - v;              // global exclusive prefix
    if (gid == 0) row_ptr[N_NODES] = N_EDGES;
}

// ---------------------------------------------------------------------------
// Phase C: counting-sort of each chunk by bucket. Per-chunk histogram loaded
// from hist (part_count reuse, R6-verified). Internal scan = wave-scan.
// ---------------------------------------------------------------------------
__global__ __launch_bounds__(1024)
void part_scatter(const int* __restrict__ rows,
                  const int* __restrict__ cols,
                  const float* __restrict__ vals,
                  const int* __restrict__ hist,
                  const int* __restrict__ sofs,
                  unsigned int* __restrict__ ppay,
                  unsigned short* __restrict__ prloc) {
    __shared__ int lcnt[PART_K];            // counts -> cursors
    __shared__ int lbase[PART_K];           // local exclusive base
    __shared__ int gbase[PART_K];           // global base for (bucket, this block)
    __shared__ int ws[16];
    __shared__ unsigned int   pay[CHUNK];   // 19.5 KB
    __shared__ unsigned short rl[CHUNK];    // 9.8 KB
    __shared__ unsigned short bk[CHUNK];    // 9.8 KB
    int b = blockIdx.x;
    int tid = threadIdx.x;                  // blockDim == 1024
    int myp = swz(b);
    for (int i = tid; i < PART_K; i += 1024) {
        lcnt[i] = hist[b * PART_K + i];     // reuse phase-A counts
        gbase[i] = sofs[i * PART_B + myp];
    }
    __syncthreads();
    int beg = b * CHUNK;
    int end = min(beg + CHUNK, N_EDGES);
    int n = end - beg;
    int v = (tid < PART_K) ? lcnt[tid] : 0;
    int incl = bscan1024(v, ws);
    int excl = incl - v;
    __syncthreads();                        // lcnt reads above done before overwrite
    if (tid < PART_K) {
        lbase[tid] = excl;
        lcnt[tid] = excl;                   // cursor
    }
    __syncthreads();
    for (int i = beg + tid * 4; i < end; i += 4096) {
        int4 r4 = *(const int4*)(rows + i);
        int4 c4 = *(const int4*)(cols + i);
        float4 v4 = *(const float4*)(vals + i);
        int rr[4] = {r4.x, r4.y, r4.z, r4.w};
        int cc[4] = {c4.x, c4.y, c4.z, c4.w};
        float vv[4] = {v4.x, v4.y, v4.z, v4.w};
        #pragma unroll
        for (int j = 0; j < 4; ++j) {
            int r = rr[j];
            int k = r >> 9;
            int pcur = atomicAdd(&lcnt[k], 1);
            unsigned int q = (unsigned int)min(8191, (int)(vv[j] * VAL_SCALE + 0.5f));
            pay[pcur] = (unsigned int)cc[j] | (q << 19);
            rl[pcur] = (unsigned short)(r & 511);
            bk[pcur] = (unsigned short)k;
        }
    }
    __syncthreads();
    for (int i = tid; i < n; i += 1024) {
        int k = bk[i];
        int a = gbase[k] + (i - lbase[k]);
        ppay[a] = pay[i];
        prloc[a] = rl[i];
    }
}

// ---------------------------------------------------------------------------
// Phase D: one block per bucket. Count + wave-scan its 512 rows, write
// row_ptr, scatter payloads into LDS staging, write out fully coalesced.
// ---------------------------------------------------------------------------
__global__ __launch_bounds__(512)
void csr_finalize(const unsigned int* __restrict__ ppay,
                  const unsigned short* __restrict__ prloc,
                  const int* __restrict__ sofs,
                  int* __restrict__ row_ptr,
                  unsigned int* __restrict__ sorted) {
    __shared__ int cnt[ROWS_PER_BUCKET];
    __shared__ int cur[ROWS_PER_BUCKET];
    __shared__ int ws[8];
    __shared__ unsigned int obuf[FIN_CAP];       // 40 KB
    int k = blockIdx.x;
    int tid = threadIdx.x;                       // blockDim == 512
    int seg_beg = sofs[k * PART_B];
    int seg_end = (k + 1 < PART_K) ? sofs[(k + 1) * PART_B] : N_EDGES;
    int n = seg_end - seg_beg;

    cnt[tid] = 0;
    __syncthreads();
    for (int i = seg_beg + tid; i < seg_end; i += ROWS_PER_BUCKET)
        atomicAdd(&cnt[prloc[i]], 1);
    __syncthreads();

    int v = cnt[tid];
    int incl = bscan512(v, ws);
    int excl = incl - v;

    int row = k * ROWS_PER_BUCKET + tid;
    if (row < N_NODES) row_ptr[row] = seg_beg + excl;
    cur[tid] = excl;
    __syncthreads();

    if (n <= FIN_CAP) {
        for (int i = seg_beg + tid; i < seg_end; i += ROWS_PER_BUCKET) {
            int r = prloc[i];
            int lp = atomicAdd(&cur[r], 1);
            obuf[lp] = ppay[i];
        }
        __syncthreads();
        for (int i = tid; i < n; i += ROWS_PER_BUCKET)
            sorted[seg_beg + i] = obuf[i];
    } else {
        for (int i = seg_beg + tid; i < seg_end; i += ROWS_PER_BUCKET) {
            int r = prloc[i];
            int lp = atomicAdd(&cur[r], 1);
            sorted[seg_beg + lp] = ppay[i];
        }
    }
}

// ---------------------------------------------------------------------------
// fp8 decode-accumulate into a named accumulator array (scaled domain).
// ---------------------------------------------------------------------------
#define ACCF8A(vv, u, A) { \
    f32x2 g0_ = __builtin_amdgcn_cvt_pk_f32_fp8((int)(u).x, 0); \
    f32x2 g1_ = __builtin_amdgcn_cvt_pk_f32_fp8((int)(u).x, 1); \
    f32x2 g2_ = __builtin_amdgcn_cvt_pk_f32_fp8((int)(u).y, 0); \
    f32x2 g3_ = __builtin_amdgcn_cvt_pk_f32_fp8((int)(u).y, 1); \
    A[0] += (vv) * g0_.x; A[1] += (vv) * g0_.y; \
    A[2] += (vv) * g1_.x; A[3] += (vv) * g1_.y; \
    A[4] += (vv) * g2_.x; A[5] += (vv) * g2_.y; \
    A[6] += (vv) * g3_.x; A[7] += (vv) * g3_.y; }

// fp16 (half8 in a float4) decode-accumulate.
#define ACCHA(vv, r, A) { \
    const __half2* hp_ = (const __half2*)&(r); \
    float2 f0_ = __half22float2(hp_[0]); \
    float2 f1_ = __half22float2(hp_[1]); \
    float2 f2_ = __half22float2(hp_[2]); \
    float2 f3_ = __half22float2(hp_[3]); \
    A[0] += (vv) * f0_.x; A[1] += (vv) * f0_.y; \
    A[2] += (vv) * f1_.x; A[3] += (vv) * f1_.y; \
    A[4] += (vv) * f2_.x; A[5] += (vv) * f2_.y; \
    A[6] += (vv) * f3_.x; A[7] += (vv) * f3_.y; }

// ---------------------------------------------------------------------------
// SpMM layer 1: fp8 gather -> fp8 store. EXACT R5 form (79 us, VGPR 32,
// zero scratch) — epilogue untouched (R6 lesson).
// ---------------------------------------------------------------------------
__global__ __launch_bounds__(256, 6)
void spmm_f8f8(const int* __restrict__ row_ptr,
               const unsigned int* __restrict__ sorted,
               const uint2* __restrict__ xf8,
               uint2* __restrict__ yf8) {
    int t = blockIdx.x * blockDim.x + threadIdx.x;
    int row = t >> 3;
    int l8 = t & 7;
    if (row >= N_NODES) return;
    int beg = row_ptr[row];
    int end = row_ptr[row + 1];
    float acc[8] = {0.f, 0.f, 0.f, 0.f, 0.f, 0.f, 0.f, 0.f};
    int e = beg;
    for (; e + 8 <= end; e += 8) {
        unsigned int cv[8];
        #pragma unroll
        for (int j = 0; j < 8; ++j) cv[j] = sorted[e + j];
        uint2 r[8];
        #pragma unroll
        for (int j = 0; j < 8; ++j)
            r[j] = xf8[(size_t)(cv[j] & 0x7FFFF) * 8 + l8];
        #pragma unroll
        for (int j = 0; j < 8; ++j) {
            float v = (float)(cv[j] >> 19) * VAL_INV;
            ACCF8A(v, r[j], acc);
        }
    }
    for (; e + 4 <= end; e += 4) {
        unsigned int cv[4];
        #pragma unroll
        for (int j = 0; j < 4; ++j) cv[j] = sorted[e + j];
        uint2 r[4];
        #pragma unroll
        for (int j = 0; j < 4; ++j)
            r[j] = xf8[(size_t)(cv[j] & 0x7FFFF) * 8 + l8];
        #pragma unroll
        for (int j = 0; j < 4; ++j) {
            float v = (float)(cv[j] >> 19) * VAL_INV;
            ACCF8A(v, r[j], acc);
        }
    }
    for (; e < end; ++e) {
        unsigned int cv = sorted[e];
        uint2 r0 = xf8[(size_t)(cv & 0x7FFFF) * 8 + l8];
        float v = (float)(cv >> 19) * VAL_INV;
        ACCF8A(v, r0, acc);
    }
    int lo = __builtin_amdgcn_cvt_pk_fp8_f32(acc[0], acc[1], 0, 0);
    lo     = __builtin_amdgcn_cvt_pk_fp8_f32(acc[2], acc[3], lo, 1);
    int hi = __builtin_amdgcn_cvt_pk_fp8_f32(acc[4], acc[5], 0, 0);
    hi     = __builtin_amdgcn_cvt_pk_fp8_f32(acc[6], acc[7], hi, 1);
    yf8[(size_t)row * 8 + l8] = make_uint2((unsigned int)lo, (unsigned int)hi);
}

// ---------------------------------------------------------------------------
// SpMM layer 2: fp8 gather -> fp16 store.
// ---------------------------------------------------------------------------
__global__ __launch_bounds__(256, 6)
void spmm_f8f16(const int* __restrict__ row_ptr,
                const unsigned int* __restrict__ sorted,
                const uint2* __restrict__ xf8,
                __half* __restrict__ yh) {
    int t = blockIdx.x * blockDim.x + threadIdx.x;
    int row = t >> 3;
    int l8 = t & 7;
    if (row >= N_NODES) return;
    int beg = row_ptr[row];
    int end = row_ptr[row + 1];
    float acc[8] = {0.f, 0.f, 0.f, 0.f, 0.f, 0.f, 0.f, 0.f};
    int e = beg;
    for (; e + 8 <= end; e += 8) {
        unsigned int cv[8];
        #pragma unroll
        for (int j = 0; j < 8; ++j) cv[j] = sorted[e + j];
        uint2 r[8];
        #pragma unroll
        for (int j = 0; j < 8; ++j)
            r[j] = xf8[(size_t)(cv[j] & 0x7FFFF) * 8 + l8];
        #pragma unroll
        for (int j = 0; j < 8; ++j) {
            float v = (float)(cv[j] >> 19) * VAL_INV;
            ACCF8A(v, r[j], acc);
        }
    }
    for (; e + 4 <= end; e += 4) {
        unsigned int cv[4];
        #pragma unroll
        for (int j = 0; j < 4; ++j) cv[j] = sorted[e + j];
        uint2 r[4];
        #pragma unroll
        for (int j = 0; j < 4; ++j)
            r[j] = xf8[(size_t)(cv[j] & 0x7FFFF) * 8 + l8];
        #pragma unroll
        for (int j = 0; j < 4; ++j) {
            float v = (float)(cv[j] >> 19) * VAL_INV;
            ACCF8A(v, r[j], acc);
        }
    }
    for (; e < end; ++e) {
        unsigned int cv = sorted[e];
        uint2 r0 = xf8[(size_t)(cv & 0x7FFFF) * 8 + l8];
        float v = (float)(cv >> 19) * VAL_INV;
        ACCF8A(v, r0, acc);
    }
    float4 ov;
    ((__half2*)&ov)[0] = __floats2half2_rn(acc[0], acc[1]);
    ((__half2*)&ov)[1] = __floats2half2_rn(acc[2], acc[3]);
    ((__half2*)&ov)[2] = __floats2half2_rn(acc[4], acc[5]);
    ((__half2*)&ov)[3] = __floats2half2_rn(acc[6], acc[7]);
    ((float4*)yh)[(size_t)row * 8 + l8] = ov;
}

// ---------------------------------------------------------------------------
// Final: fused layer-3 + combine. 16 lanes per slot (two 8-lane sub-groups on
// alternating edge quads; __shfl_xor(8) merge). Per edge gathers x0f8[col]
// (E1 recompute) and E2h[col] (A*E2).
// out = (E0 + (E1rec + E2d + E3)/EMB_SCALE) / 4
// ---------------------------------------------------------------------------
__global__ __launch_bounds__(256, 4)
void final_kernel(const int* __restrict__ row_ptr,
                  const unsigned int* __restrict__ sorted,
                  const float* __restrict__ user_emb,
                  const float* __restrict__ item_emb,
                  const uint2* __restrict__ x0f8,
                  const __half* __restrict__ E2h,
                  const int* __restrict__ users,
                  const int* __restrict__ pos_items,
                  const int* __restrict__ neg_items,
                  float* __restrict__ out) {
    int t = blockIdx.x * blockDim.x + threadIdx.x;
    int slot = t >> 4;
    int sub  = (t >> 3) & 1;
    int l8   = t & 7;
    if (slot >= 3 * BATCH) return;
    int which = slot >> 12;          // BATCH == 4096
    int idx   = slot & (BATCH - 1);
    int node;
    if (which == 0)      node = users[idx];
    else if (which == 1) node = N_USERS + pos_items[idx];
    else                 node = N_USERS + neg_items[idx];

    const float4* e2v = (const float4*)E2h;

    float a1[8] = {0.f, 0.f, 0.f, 0.f, 0.f, 0.f, 0.f, 0.f};  // E1 recompute
    float a3[8] = {0.f, 0.f, 0.f, 0.f, 0.f, 0.f, 0.f, 0.f};  // A*E2
    int beg = row_ptr[node];
    int end = row_ptr[node + 1];
    int nq = (end - beg) >> 2;           // full quads
    for (int q = sub; q < nq; q += 2) {
        int e = beg + (q << 2);
        unsigned int cv[4];
        #pragma unroll
        for (int j = 0; j < 4; ++j) cv[j] = sorted[e + j];
        uint2 rx[4];
        float4 r2[4];
        #pragma unroll
        for (int j = 0; j < 4; ++j) {
            size_t col = (size_t)(cv[j] & 0x7FFFF);
            rx[j] = x0f8[col * 8 + l8];
            r2[j] = e2v[col * 8 + l8];
        }
        #pragma unroll
        for (int j = 0; j < 4; ++j) {
            float v = (float)(cv[j] >> 19) * VAL_INV;
            ACCF8A(v, rx[j], a1);
            ACCHA(v, r2[j], a3);
        }
    }
    if (sub == 0) {                      // tail edges (<4)
        for (int e = beg + (nq << 2); e < end; ++e) {
            unsigned int cv = sorted[e];
            size_t col = (size_t)(cv & 0x7FFFF);
            uint2 rx = x0f8[col * 8 + l8];
            float4 r2 = e2v[col * 8 + l8];
            float v = (float)(cv >> 19) * VAL_INV;
            ACCF8A(v, rx, a1);
            ACCHA(v, r2, a3);
        }
    }
    // merge the two sub-groups (lane ^ 8 swap-add)
    #pragma unroll
    for (int i = 0; i < 8; ++i) {
        a1[i] += __shfl_xor(a1[i], 8);
        a3[i] += __shfl_xor(a3[i], 8);
    }
    if (sub) return;

    const float* t0 = (node < N_USERS) ? (user_emb + (size_t)node * 64)
                                       : (item_emb + (size_t)(node - N_USERS) * 64);
    float4 e0a = ((const float4*)t0)[l8 * 2];
    float4 e0b = ((const float4*)t0)[l8 * 2 + 1];

    float4 e2c = e2v[(size_t)node * 8 + l8];
    const __half2* h2 = (const __half2*)&e2c;
    float e2[8];
    {
        float2 b0 = __half22float2(h2[0]), b1 = __half22float2(h2[1]);
        float2 b2 = __half22float2(h2[2]), b3 = __half22float2(h2[3]);
        e2[0]=b0.x; e2[1]=b0.y; e2[2]=b1.x; e2[3]=b1.y;
        e2[4]=b2.x; e2[5]=b2.y; e2[6]=b3.x; e2[7]=b3.y;
    }
    float4 ra, rb;
    ra.x = (e0a.x + (a1[0] + e2[0] + a3[0]) * EMB_INV) * 0.25f;
    ra.y = (e0a.y + (a1[1] + e2[1] + a3[1]) * EMB_INV) * 0.25f;
    ra.z = (e0a.z + (a1[2] + e2[2] + a3[2]) * EMB_INV) * 0.25f;
    ra.w = (e0a.w + (a1[3] + e2[3] + a3[3]) * EMB_INV) * 0.25f;
    rb.x = (e0b.x + (a1[4] + e2[4] + a3[4]) * EMB_INV) * 0.25f;
    rb.y = (e0b.y + (a1[5] + e2[5] + a3[5]) * EMB_INV) * 0.25f;
    rb.z = (e0b.z + (a1[6] + e2[6] + a3[6]) * EMB_INV) * 0.25f;
    rb.w = (e0b.w + (a1[7] + e2[7] + a3[7]) * EMB_INV) * 0.25f;
    ((float4*)out)[(size_t)slot * 16 + l8 * 2]     = ra;
    ((float4*)out)[(size_t)slot * 16 + l8 * 2 + 1] = rb;
}

// ---------------------------------------------------------------------------
extern "C" void kernel_launch(void* const* d_in, const int* in_sizes, int n_in,
                              void* d_out, int out_size, void* d_ws, size_t ws_size,
                              hipStream_t stream) {
    const float* user_emb  = (const float*)d_in[0];
    const float* item_emb  = (const float*)d_in[1];
    const float* adj_vals  = (const float*)d_in[2];
    const int*   adj_rows  = (const int*)d_in[3];
    const int*   adj_cols  = (const int*)d_in[4];
    const int*   users     = (const int*)d_in[5];
    const int*   pos_items = (const int*)d_in[6];
    const int*   neg_items = (const int*)d_in[7];
    float* out = (float*)d_out;

    char* ws = (char*)d_ws;
    size_t off = 0;
    auto alloc = [&](size_t bytes) -> void* {
        void* p = ws + off;
        off = (off + bytes + 255) & ~(size_t)255;
        return p;
    };
    int*  hist    = (int*) alloc((size_t)(PART_L + 32) * sizeof(int));  // 2.4 MB
    int*  sofs    = (int*) alloc((size_t)(PART_L + 32) * sizeof(int));  // 2.4 MB
    int*  row_ptr = (int*) alloc((size_t)(N_NODES + 32) * sizeof(int));
    unsigned long long* lb_state = (unsigned long long*)alloc((size_t)(SCAN_NB + 32) * sizeof(unsigned long long));
    int*  ticket  = (int*) alloc(256);
    unsigned int*   ppay  = (unsigned int*)  alloc((size_t)N_EDGES * sizeof(unsigned int));   // 20 MB
    unsigned short* prloc = (unsigned short*)alloc((size_t)N_EDGES * sizeof(unsigned short)); // 10 MB
    unsigned int* sorted = (unsigned int*)alloc((size_t)N_EDGES * sizeof(unsigned int)); // 20 MB
    uint2*  x0f8 = (uint2*) alloc((size_t)N_NODES * EMBED_DIM);                    // 19.2 MB (fp8)
    uint2*  E1f8 = (uint2*) alloc((size_t)N_NODES * EMBED_DIM);                    // 19.2 MB (fp8)
    __half* E2h  = (__half*)alloc((size_t)N_NODES * EMBED_DIM * sizeof(__half));   // 38.4 MB (fp16)

    const int TB = 256;

    // 1. fused histogram + fp8 convert + scan-state zero
    pc_conv<<<PART_B + CONV_BLOCKS + 1, 1024, 0, stream>>>(
        adj_rows, hist, user_emb, item_emb, x0f8, lb_state, ticket);
    // 2. single-pass decoupled-lookback scan -> sofs, row_ptr[N]
    scan_lookback<<<SCAN_NB, SCAN_T, 0, stream>>>(hist, lb_state, ticket, sofs, row_ptr);
    // 3. bucket-grouped scatter (split payload arrays)
    part_scatter<<<PART_B, 1024, 0, stream>>>(adj_rows, adj_cols, adj_vals, hist, sofs, ppay, prloc);
    // 4. per-bucket row sort -> CSR
    csr_finalize<<<PART_K, ROWS_PER_BUCKET, 0, stream>>>(ppay, prloc, sofs, row_ptr, sorted);
    // 5-6. SpMM layers (fp8 gathers)
    int spmm_blocks = (N_NODES * 8 + TB - 1) / TB;   // 9375 blocks
    spmm_f8f8 <<<spmm_blocks, TB, 0, stream>>>(row_ptr, sorted, x0f8, E1f8);
    spmm_f8f16<<<spmm_blocks, TB, 0, stream>>>(row_ptr, sorted, E1f8, E2h);
    // 7. layer 3 (batch rows) + combine
    int final_blocks = (3 * BATCH * 16 + TB - 1) / TB; // 768 blocks
    final_kernel<<<final_blocks, TB, 0, stream>>>(
        row_ptr, sorted, user_emb, item_emb, x0f8, E2h, users, pos_items, neg_items, out);
}

// Round 9
// 384.132 us; speedup vs baseline: 1.3857x; 1.3857x over previous
//
#include <hip/hip_runtime.h>
#include <hip/hip_fp16.h>
#include <stdint.h>

#define N_USERS   200000
#define N_ITEMS   100000
#define N_NODES   300000
#define EMBED_DIM 64
#define N_EDGES   5000000
#define BATCH     4096

// ---- two-level partition geometry ----
#define ROWS_PER_BUCKET 512
#define PART_K 586                         // ceil(300000/512) buckets
#define PART_B 1024                        // partition blocks
#define CHUNK  4884                        // div by 4; 1024*4884 >= 5M; all blocks get 4|count
#define PART_L (PART_K * PART_B)           // 600064
#define SCAN_T 1024
#define SCAN_NB (PART_L / SCAN_T)          // 586 exactly

#define VAL_SCALE 81920.0f                 // maps [0,0.1) -> [0,8192)
#define VAL_INV   (1.0f / 81920.0f)
#define FIN_CAP   10240                    // LDS staging capacity (bucket mean 8533, sd 92)

#define CONV_BLOCKS ((N_NODES * 8 + 1023) / 1024)   // 2344

// fp8 storage scale (R3/R4 notes): scaled values sit in e4m3 normal range.
// fp8 ONLY on the two 5M-gather tables (x0, E1). E1's direct read in the
// combine is RECOMPUTED from x0 gathers inside final_kernel (R5 mechanism).
// R6 lesson: no conditional epilogues in the spmm loop (allocator spills).
// R8 lesson: decoupled-lookback scan serializes behind uncoalesced hist
// loads (163 us) — independent-block scans overlap those latencies; keep
// the two-kernel scan.
#define EMB_SCALE 1024.0f
#define EMB_INV   (1.0f / 1024.0f)

typedef float f32x2 __attribute__((ext_vector_type(2)));

// XCD-grouping permutation of run order within a bucket (bijection on [0,1024))
__device__ __forceinline__ int swz(int b)     { return ((b & 7) << 7) | (b >> 3); }

// ---------------------------------------------------------------------------
// Wave-level scans: 64-lane shfl_up inclusive scan; block scans with only
// 2 barriers.
// ---------------------------------------------------------------------------
__device__ __forceinline__ int wscan_incl(int x) {
    #pragma unroll
    for (int d = 1; d < 64; d <<= 1) {
        int t = __shfl_up(x, d);
        if ((int)(threadIdx.x & 63) >= d) x += t;
    }
    return x;
}

// 1024-thread block inclusive scan; ws = LDS int[16]; ws[15] = block total.
__device__ __forceinline__ int bscan1024(int v, int* ws) {
    int tid = threadIdx.x, lane = tid & 63, wv = tid >> 6;
    int x = wscan_incl(v);
    if (lane == 63) ws[wv] = x;
    __syncthreads();
    if (tid < 16) {
        int s = ws[tid];
        #pragma unroll
        for (int d = 1; d < 16; d <<= 1) {
            int t = __shfl_up(s, d, 16);
            if (tid >= d) s += t;
        }
        ws[tid] = s;
    }
    __syncthreads();
    return x + (wv ? ws[wv - 1] : 0);
}

// 512-thread block inclusive scan; ws = LDS int[8]; ws[7] = block total.
__device__ __forceinline__ int bscan512(int v, int* ws) {
    int tid = threadIdx.x, lane = tid & 63, wv = tid >> 6;
    int x = wscan_incl(v);
    if (lane == 63) ws[wv] = x;
    __syncthreads();
    if (tid < 8) {
        int s = ws[tid];
        #pragma unroll
        for (int d = 1; d < 8; d <<= 1) {
            int t = __shfl_up(s, d, 8);
            if (tid >= d) s += t;
        }
        ws[tid] = s;
    }
    __syncthreads();
    return x + (wv ? ws[wv - 1] : 0);
}

// ---------------------------------------------------------------------------
// Fused: part_count histogram (blocks [0,PART_B)) + fp32->fp8 convert
// (blocks [PART_B, PART_B+CONV_BLOCKS)). Independent work, one launch.
// ---------------------------------------------------------------------------
__global__ __launch_bounds__(1024)
void pc_conv(const int* __restrict__ rows, int* __restrict__ hist,
             const float* __restrict__ ue, const float* __restrict__ ie,
             uint2* __restrict__ xf8) {
    int bx = blockIdx.x;
    int tid = threadIdx.x;
    if (bx < PART_B) {
        __shared__ int h[PART_K];
        for (int i = tid; i < PART_K; i += 1024) h[i] = 0;
        __syncthreads();
        int beg = bx * CHUNK;
        int end = min(beg + CHUNK, N_EDGES);
        for (int i = beg + tid * 4; i < end; i += 4096) {
            int4 r4 = *(const int4*)(rows + i);
            atomicAdd(&h[r4.x >> 9], 1);
            atomicAdd(&h[r4.y >> 9], 1);
            atomicAdd(&h[r4.z >> 9], 1);
            atomicAdd(&h[r4.w >> 9], 1);
        }
        __syncthreads();
        for (int i = tid; i < PART_K; i += 1024)
            hist[bx * PART_K + i] = h[i];
        return;
    }
    int t = (bx - PART_B) * 1024 + tid;
    if (t >= N_NODES * 8) return;
    int flat = t * 8;
    int row = flat >> 6;
    int off = flat & 63;
    const float* src = (row < N_USERS) ? (ue + (size_t)row * 64 + off)
                                       : (ie + (size_t)(row - N_USERS) * 64 + off);
    float4 a = ((const float4*)src)[0];
    float4 b = ((const float4*)src)[1];
    int lo = __builtin_amdgcn_cvt_pk_fp8_f32(a.x * EMB_SCALE, a.y * EMB_SCALE, 0, 0);
    lo     = __builtin_amdgcn_cvt_pk_fp8_f32(a.z * EMB_SCALE, a.w * EMB_SCALE, lo, 1);
    int hi = __builtin_amdgcn_cvt_pk_fp8_f32(b.x * EMB_SCALE, b.y * EMB_SCALE, 0, 0);
    hi     = __builtin_amdgcn_cvt_pk_fp8_f32(b.z * EMB_SCALE, b.w * EMB_SCALE, hi, 1);
    xf8[t] = make_uint2((unsigned int)lo, (unsigned int)hi);
}

// ---------------------------------------------------------------------------
// Scan pass 1: per-block (bucket) scan in LOGICAL order gid = k*PART_B + p,
// p = swz(b). Independent blocks -> uncoalesced hist loads overlap (R8
// lesson: do NOT serialize behind these loads).
// ---------------------------------------------------------------------------
__global__ __launch_bounds__(1024)
void scan_partial(const int* __restrict__ hist,
                  int* __restrict__ local_scan,
                  int* __restrict__ block_sums) {
    __shared__ int ws[16];
    int tid = threadIdx.x;
    int gid = blockIdx.x * SCAN_T + tid;
    int p = tid;
    int b = ((p & 127) << 3) | (p >> 7); // inverse swizzle
    int v = hist[b * PART_K + blockIdx.x];
    int incl = bscan1024(v, ws);
    local_scan[gid] = incl - v;
    if (tid == SCAN_T - 1) block_sums[blockIdx.x] = incl;
}

// Scan pass 2: each block redundantly scans the 586 block sums (cheap),
// takes its exclusive prefix, applies it.
__global__ __launch_bounds__(1024)
void scan_addoff(const int* __restrict__ local_scan,
                 const int* __restrict__ block_sums,
                 int* __restrict__ sofs,
                 int* __restrict__ row_ptr) {
    __shared__ int ws[16];
    __shared__ int sh[SCAN_NB];
    int tid = threadIdx.x;
    int v = (tid < SCAN_NB) ? block_sums[tid] : 0;
    int incl = bscan1024(v, ws);
    if (tid < SCAN_NB) sh[tid] = incl;
    __syncthreads();
    int base = (blockIdx.x == 0) ? 0 : sh[blockIdx.x - 1];  // exclusive prefix
    int gid = blockIdx.x * SCAN_T + tid;
    sofs[gid] = local_scan[gid] + base;
    if (gid == 0) row_ptr[N_NODES] = N_EDGES;
}

// ---------------------------------------------------------------------------
// Phase C: counting-sort of each chunk by bucket. Per-chunk histogram loaded
// from hist (part_count reuse, R6-verified). Internal scan = wave-scan.
// ---------------------------------------------------------------------------
__global__ __launch_bounds__(1024)
void part_scatter(const int* __restrict__ rows,
                  const int* __restrict__ cols,
                  const float* __restrict__ vals,
                  const int* __restrict__ hist,
                  const int* __restrict__ sofs,
                  unsigned int* __restrict__ ppay,
                  unsigned short* __restrict__ prloc) {
    __shared__ int lcnt[PART_K];            // counts -> cursors
    __shared__ int lbase[PART_K];           // local exclusive base
    __shared__ int gbase[PART_K];           // global base for (bucket, this block)
    __shared__ int ws[16];
    __shared__ unsigned int   pay[CHUNK];   // 19.5 KB
    __shared__ unsigned short rl[CHUNK];    // 9.8 KB
    __shared__ unsigned short bk[CHUNK];    // 9.8 KB
    int b = blockIdx.x;
    int tid = threadIdx.x;                  // blockDim == 1024
    int myp = swz(b);
    for (int i = tid; i < PART_K; i += 1024) {
        lcnt[i] = hist[b * PART_K + i];     // reuse phase-A counts
        gbase[i] = sofs[i * PART_B + myp];
    }
    __syncthreads();
    int beg = b * CHUNK;
    int end = min(beg + CHUNK, N_EDGES);
    int n = end - beg;
    int v = (tid < PART_K) ? lcnt[tid] : 0;
    int incl = bscan1024(v, ws);
    int excl = incl - v;
    __syncthreads();                        // lcnt reads done before overwrite
    if (tid < PART_K) {
        lbase[tid] = excl;
        lcnt[tid] = excl;                   // cursor
    }
    __syncthreads();
    for (int i = beg + tid * 4; i < end; i += 4096) {
        int4 r4 = *(const int4*)(rows + i);
        int4 c4 = *(const int4*)(cols + i);
        float4 v4 = *(const float4*)(vals + i);
        int rr[4] = {r4.x, r4.y, r4.z, r4.w};
        int cc[4] = {c4.x, c4.y, c4.z, c4.w};
        float vv[4] = {v4.x, v4.y, v4.z, v4.w};
        #pragma unroll
        for (int j = 0; j < 4; ++j) {
            int r = rr[j];
            int k = r >> 9;
            int pcur = atomicAdd(&lcnt[k], 1);
            unsigned int q = (unsigned int)min(8191, (int)(vv[j] * VAL_SCALE + 0.5f));
            pay[pcur] = (unsigned int)cc[j] | (q << 19);
            rl[pcur] = (unsigned short)(r & 511);
            bk[pcur] = (unsigned short)k;
        }
    }
    __syncthreads();
    for (int i = tid; i < n; i += 1024) {
        int k = bk[i];
        int a = gbase[k] + (i - lbase[k]);
        ppay[a] = pay[i];
        prloc[a] = rl[i];
    }
}

// ---------------------------------------------------------------------------
// Phase D: one block per bucket. Count + wave-scan its 512 rows, write
// row_ptr, scatter payloads into LDS staging, write out fully coalesced.
// ---------------------------------------------------------------------------
__global__ __launch_bounds__(512)
void csr_finalize(const unsigned int* __restrict__ ppay,
                  const unsigned short* __restrict__ prloc,
                  const int* __restrict__ sofs,
                  int* __restrict__ row_ptr,
                  unsigned int* __restrict__ sorted) {
    __shared__ int cnt[ROWS_PER_BUCKET];
    __shared__ int cur[ROWS_PER_BUCKET];
    __shared__ int ws[8];
    __shared__ unsigned int obuf[FIN_CAP];       // 40 KB
    int k = blockIdx.x;
    int tid = threadIdx.x;                       // blockDim == 512
    int seg_beg = sofs[k * PART_B];
    int seg_end = (k + 1 < PART_K) ? sofs[(k + 1) * PART_B] : N_EDGES;
    int n = seg_end - seg_beg;

    cnt[tid] = 0;
    __syncthreads();
    for (int i = seg_beg + tid; i < seg_end; i += ROWS_PER_BUCKET)
        atomicAdd(&cnt[prloc[i]], 1);
    __syncthreads();

    int v = cnt[tid];
    int incl = bscan512(v, ws);
    int excl = incl - v;

    int row = k * ROWS_PER_BUCKET + tid;
    if (row < N_NODES) row_ptr[row] = seg_beg + excl;
    cur[tid] = excl;
    __syncthreads();

    if (n <= FIN_CAP) {
        for (int i = seg_beg + tid; i < seg_end; i += ROWS_PER_BUCKET) {
            int r = prloc[i];
            int lp = atomicAdd(&cur[r], 1);
            obuf[lp] = ppay[i];
        }
        __syncthreads();
        for (int i = tid; i < n; i += ROWS_PER_BUCKET)
            sorted[seg_beg + i] = obuf[i];
    } else {
        for (int i = seg_beg + tid; i < seg_end; i += ROWS_PER_BUCKET) {
            int r = prloc[i];
            int lp = atomicAdd(&cur[r], 1);
            sorted[seg_beg + lp] = ppay[i];
        }
    }
}

// ---------------------------------------------------------------------------
// fp8 decode-accumulate into a named accumulator array (scaled domain).
// ---------------------------------------------------------------------------
#define ACCF8A(vv, u, A) { \
    f32x2 g0_ = __builtin_amdgcn_cvt_pk_f32_fp8((int)(u).x, 0); \
    f32x2 g1_ = __builtin_amdgcn_cvt_pk_f32_fp8((int)(u).x, 1); \
    f32x2 g2_ = __builtin_amdgcn_cvt_pk_f32_fp8((int)(u).y, 0); \
    f32x2 g3_ = __builtin_amdgcn_cvt_pk_f32_fp8((int)(u).y, 1); \
    A[0] += (vv) * g0_.x; A[1] += (vv) * g0_.y; \
    A[2] += (vv) * g1_.x; A[3] += (vv) * g1_.y; \
    A[4] += (vv) * g2_.x; A[5] += (vv) * g2_.y; \
    A[6] += (vv) * g3_.x; A[7] += (vv) * g3_.y; }

// fp16 (half8 in a float4) decode-accumulate.
#define ACCHA(vv, r, A) { \
    const __half2* hp_ = (const __half2*)&(r); \
    float2 f0_ = __half22float2(hp_[0]); \
    float2 f1_ = __half22float2(hp_[1]); \
    float2 f2_ = __half22float2(hp_[2]); \
    float2 f3_ = __half22float2(hp_[3]); \
    A[0] += (vv) * f0_.x; A[1] += (vv) * f0_.y; \
    A[2] += (vv) * f1_.x; A[3] += (vv) * f1_.y; \
    A[4] += (vv) * f2_.x; A[5] += (vv) * f2_.y; \
    A[6] += (vv) * f3_.x; A[7] += (vv) * f3_.y; }

// ---------------------------------------------------------------------------
// SpMM layer 1: fp8 gather -> fp8 store. EXACT R5 form (79 us, VGPR 32,
// zero scratch) — epilogue untouched (R6 lesson).
// ---------------------------------------------------------------------------
__global__ __launch_bounds__(256, 6)
void spmm_f8f8(const int* __restrict__ row_ptr,
               const unsigned int* __restrict__ sorted,
               const uint2* __restrict__ xf8,
               uint2* __restrict__ yf8) {
    int t = blockIdx.x * blockDim.x + threadIdx.x;
    int row = t >> 3;
    int l8 = t & 7;
    if (row >= N_NODES) return;
    int beg = row_ptr[row];
    int end = row_ptr[row + 1];
    float acc[8] = {0.f, 0.f, 0.f, 0.f, 0.f, 0.f, 0.f, 0.f};
    int e = beg;
    for (; e + 8 <= end; e += 8) {
        unsigned int cv[8];
        #pragma unroll
        for (int j = 0; j < 8; ++j) cv[j] = sorted[e + j];
        uint2 r[8];
        #pragma unroll
        for (int j = 0; j < 8; ++j)
            r[j] = xf8[(size_t)(cv[j] & 0x7FFFF) * 8 + l8];
        #pragma unroll
        for (int j = 0; j < 8; ++j) {
            float v = (float)(cv[j] >> 19) * VAL_INV;
            ACCF8A(v, r[j], acc);
        }
    }
    for (; e + 4 <= end; e += 4) {
        unsigned int cv[4];
        #pragma unroll
        for (int j = 0; j < 4; ++j) cv[j] = sorted[e + j];
        uint2 r[4];
        #pragma unroll
        for (int j = 0; j < 4; ++j)
            r[j] = xf8[(size_t)(cv[j] & 0x7FFFF) * 8 + l8];
        #pragma unroll
        for (int j = 0; j < 4; ++j) {
            float v = (float)(cv[j] >> 19) * VAL_INV;
            ACCF8A(v, r[j], acc);
        }
    }
    for (; e < end; ++e) {
        unsigned int cv = sorted[e];
        uint2 r0 = xf8[(size_t)(cv & 0x7FFFF) * 8 + l8];
        float v = (float)(cv >> 19) * VAL_INV;
        ACCF8A(v, r0, acc);
    }
    int lo = __builtin_amdgcn_cvt_pk_fp8_f32(acc[0], acc[1], 0, 0);
    lo     = __builtin_amdgcn_cvt_pk_fp8_f32(acc[2], acc[3], lo, 1);
    int hi = __builtin_amdgcn_cvt_pk_fp8_f32(acc[4], acc[5], 0, 0);
    hi     = __builtin_amdgcn_cvt_pk_fp8_f32(acc[6], acc[7], hi, 1);
    yf8[(size_t)row * 8 + l8] = make_uint2((unsigned int)lo, (unsigned int)hi);
}

// ---------------------------------------------------------------------------
// SpMM layer 2: fp8 gather -> fp16 store.
// ---------------------------------------------------------------------------
__global__ __launch_bounds__(256, 6)
void spmm_f8f16(const int* __restrict__ row_ptr,
                const unsigned int* __restrict__ sorted,
                const uint2* __restrict__ xf8,
                __half* __restrict__ yh) {
    int t = blockIdx.x * blockDim.x + threadIdx.x;
    int row = t >> 3;
    int l8 = t & 7;
    if (row >= N_NODES) return;
    int beg = row_ptr[row];
    int end = row_ptr[row + 1];
    float acc[8] = {0.f, 0.f, 0.f, 0.f, 0.f, 0.f, 0.f, 0.f};
    int e = beg;
    for (; e + 8 <= end; e += 8) {
        unsigned int cv[8];
        #pragma unroll
        for (int j = 0; j < 8; ++j) cv[j] = sorted[e + j];
        uint2 r[8];
        #pragma unroll
        for (int j = 0; j < 8; ++j)
            r[j] = xf8[(size_t)(cv[j] & 0x7FFFF) * 8 + l8];
        #pragma unroll
        for (int j = 0; j < 8; ++j) {
            float v = (float)(cv[j] >> 19) * VAL_INV;
            ACCF8A(v, r[j], acc);
        }
    }
    for (; e + 4 <= end; e += 4) {
        unsigned int cv[4];
        #pragma unroll
        for (int j = 0; j < 4; ++j) cv[j] = sorted[e + j];
        uint2 r[4];
        #pragma unroll
        for (int j = 0; j < 4; ++j)
            r[j] = xf8[(size_t)(cv[j] & 0x7FFFF) * 8 + l8];
        #pragma unroll
        for (int j = 0; j < 4; ++j) {
            float v = (float)(cv[j] >> 19) * VAL_INV;
            ACCF8A(v, r[j], acc);
        }
    }
    for (; e < end; ++e) {
        unsigned int cv = sorted[e];
        uint2 r0 = xf8[(size_t)(cv & 0x7FFFF) * 8 + l8];
        float v = (float)(cv >> 19) * VAL_INV;
        ACCF8A(v, r0, acc);
    }
    float4 ov;
    ((__half2*)&ov)[0] = __floats2half2_rn(acc[0], acc[1]);
    ((__half2*)&ov)[1] = __floats2half2_rn(acc[2], acc[3]);
    ((__half2*)&ov)[2] = __floats2half2_rn(acc[4], acc[5]);
    ((__half2*)&ov)[3] = __floats2half2_rn(acc[6], acc[7]);
    ((float4*)yh)[(size_t)row * 8 + l8] = ov;
}

// ---------------------------------------------------------------------------
// Final: fused layer-3 + combine. 16 lanes per slot (two 8-lane sub-groups on
// alternating edge quads; __shfl_xor(8) merge). Per edge gathers x0f8[col]
// (E1 recompute) and E2h[col] (A*E2).
// out = (E0 + (E1rec + E2d + E3)/EMB_SCALE) / 4
// ---------------------------------------------------------------------------
__global__ __launch_bounds__(256, 4)
void final_kernel(const int* __restrict__ row_ptr,
                  const unsigned int* __restrict__ sorted,
                  const float* __restrict__ user_emb,
                  const float* __restrict__ item_emb,
                  const uint2* __restrict__ x0f8,
                  const __half* __restrict__ E2h,
                  const int* __restrict__ users,
                  const int* __restrict__ pos_items,
                  const int* __restrict__ neg_items,
                  float* __restrict__ out) {
    int t = blockIdx.x * blockDim.x + threadIdx.x;
    int slot = t >> 4;
    int sub  = (t >> 3) & 1;
    int l8   = t & 7;
    if (slot >= 3 * BATCH) return;
    int which = slot >> 12;          // BATCH == 4096
    int idx   = slot & (BATCH - 1);
    int node;
    if (which == 0)      node = users[idx];
    else if (which == 1) node = N_USERS + pos_items[idx];
    else                 node = N_USERS + neg_items[idx];

    const float4* e2v = (const float4*)E2h;

    float a1[8] = {0.f, 0.f, 0.f, 0.f, 0.f, 0.f, 0.f, 0.f};  // E1 recompute
    float a3[8] = {0.f, 0.f, 0.f, 0.f, 0.f, 0.f, 0.f, 0.f};  // A*E2
    int beg = row_ptr[node];
    int end = row_ptr[node + 1];
    int nq = (end - beg) >> 2;           // full quads
    for (int q = sub; q < nq; q += 2) {
        int e = beg + (q << 2);
        unsigned int cv[4];
        #pragma unroll
        for (int j = 0; j < 4; ++j) cv[j] = sorted[e + j];
        uint2 rx[4];
        float4 r2[4];
        #pragma unroll
        for (int j = 0; j < 4; ++j) {
            size_t col = (size_t)(cv[j] & 0x7FFFF);
            rx[j] = x0f8[col * 8 + l8];
            r2[j] = e2v[col * 8 + l8];
        }
        #pragma unroll
        for (int j = 0; j < 4; ++j) {
            float v = (float)(cv[j] >> 19) * VAL_INV;
            ACCF8A(v, rx[j], a1);
            ACCHA(v, r2[j], a3);
        }
    }
    if (sub == 0) {                      // tail edges (<4)
        for (int e = beg + (nq << 2); e < end; ++e) {
            unsigned int cv = sorted[e];
            size_t col = (size_t)(cv & 0x7FFFF);
            uint2 rx = x0f8[col * 8 + l8];
            float4 r2 = e2v[col * 8 + l8];
            float v = (float)(cv >> 19) * VAL_INV;
            ACCF8A(v, rx, a1);
            ACCHA(v, r2, a3);
        }
    }
    // merge the two sub-groups (lane ^ 8 swap-add)
    #pragma unroll
    for (int i = 0; i < 8; ++i) {
        a1[i] += __shfl_xor(a1[i], 8);
        a3[i] += __shfl_xor(a3[i], 8);
    }
    if (sub) return;

    const float* t0 = (node < N_USERS) ? (user_emb + (size_t)node * 64)
                                       : (item_emb + (size_t)(node - N_USERS) * 64);
    float4 e0a = ((const float4*)t0)[l8 * 2];
    float4 e0b = ((const float4*)t0)[l8 * 2 + 1];

    float4 e2c = e2v[(size_t)node * 8 + l8];
    const __half2* h2 = (const __half2*)&e2c;
    float e2[8];
    {
        float2 b0 = __half22float2(h2[0]), b1 = __half22float2(h2[1]);
        float2 b2 = __half22float2(h2[2]), b3 = __half22float2(h2[3]);
        e2[0]=b0.x; e2[1]=b0.y; e2[2]=b1.x; e2[3]=b1.y;
        e2[4]=b2.x; e2[5]=b2.y; e2[6]=b3.x; e2[7]=b3.y;
    }
    float4 ra, rb;
    ra.x = (e0a.x + (a1[0] + e2[0] + a3[0]) * EMB_INV) * 0.25f;
    ra.y = (e0a.y + (a1[1] + e2[1] + a3[1]) * EMB_INV) * 0.25f;
    ra.z = (e0a.z + (a1[2] + e2[2] + a3[2]) * EMB_INV) * 0.25f;
    ra.w = (e0a.w + (a1[3] + e2[3] + a3[3]) * EMB_INV) * 0.25f;
    rb.x = (e0b.x + (a1[4] + e2[4] + a3[4]) * EMB_INV) * 0.25f;
    rb.y = (e0b.y + (a1[5] + e2[5] + a3[5]) * EMB_INV) * 0.25f;
    rb.z = (e0b.z + (a1[6] + e2[6] + a3[6]) * EMB_INV) * 0.25f;
    rb.w = (e0b.w + (a1[7] + e2[7] + a3[7]) * EMB_INV) * 0.25f;
    ((float4*)out)[(size_t)slot * 16 + l8 * 2]     = ra;
    ((float4*)out)[(size_t)slot * 16 + l8 * 2 + 1] = rb;
}

// ---------------------------------------------------------------------------
extern "C" void kernel_launch(void* const* d_in, const int* in_sizes, int n_in,
                              void* d_out, int out_size, void* d_ws, size_t ws_size,
                              hipStream_t stream) {
    const float* user_emb  = (const float*)d_in[0];
    const float* item_emb  = (const float*)d_in[1];
    const float* adj_vals  = (const float*)d_in[2];
    const int*   adj_rows  = (const int*)d_in[3];
    const int*   adj_cols  = (const int*)d_in[4];
    const int*   users     = (const int*)d_in[5];
    const int*   pos_items = (const int*)d_in[6];
    const int*   neg_items = (const int*)d_in[7];
    float* out = (float*)d_out;

    char* ws = (char*)d_ws;
    size_t off = 0;
    auto alloc = [&](size_t bytes) -> void* {
        void* p = ws + off;
        off = (off + bytes + 255) & ~(size_t)255;
        return p;
    };
    int*  hist       = (int*) alloc((size_t)(PART_L + 32) * sizeof(int));  // 2.4 MB
    int*  local_scan = (int*) alloc((size_t)(PART_L + 32) * sizeof(int));  // 2.4 MB
    int*  sofs       = (int*) alloc((size_t)(PART_L + 32) * sizeof(int));  // 2.4 MB
    int*  block_sums = (int*) alloc((size_t)(SCAN_NB + 32) * sizeof(int));
    int*  row_ptr    = (int*) alloc((size_t)(N_NODES + 32) * sizeof(int));
    unsigned int*   ppay  = (unsigned int*)  alloc((size_t)N_EDGES * sizeof(unsigned int));   // 20 MB
    unsigned short* prloc = (unsigned short*)alloc((size_t)N_EDGES * sizeof(unsigned short)); // 10 MB
    unsigned int* sorted = (unsigned int*)alloc((size_t)N_EDGES * sizeof(unsigned int)); // 20 MB
    uint2*  x0f8 = (uint2*) alloc((size_t)N_NODES * EMBED_DIM);                    // 19.2 MB (fp8)
    uint2*  E1f8 = (uint2*) alloc((size_t)N_NODES * EMBED_DIM);                    // 19.2 MB (fp8)
    __half* E2h  = (__half*)alloc((size_t)N_NODES * EMBED_DIM * sizeof(__half));   // 38.4 MB (fp16)

    const int TB = 256;

    // 1. fused histogram + fp8 convert
    pc_conv<<<PART_B + CONV_BLOCKS, 1024, 0, stream>>>(
        adj_rows, hist, user_emb, item_emb, x0f8);
    // 2-3. two-pass scan (independent blocks; R8 lesson)
    scan_partial<<<SCAN_NB, SCAN_T, 0, stream>>>(hist, local_scan, block_sums);
    scan_addoff<<<SCAN_NB, SCAN_T, 0, stream>>>(local_scan, block_sums, sofs, row_ptr);
    // 4. bucket-grouped scatter (split payload arrays)
    part_scatter<<<PART_B, 1024, 0, stream>>>(adj_rows, adj_cols, adj_vals, hist, sofs, ppay, prloc);
    // 5. per-bucket row sort -> CSR
    csr_finalize<<<PART_K, ROWS_PER_BUCKET, 0, stream>>>(ppay, prloc, sofs, row_ptr, sorted);
    // 6-7. SpMM layers (fp8 gathers)
    int spmm_blocks = (N_NODES * 8 + TB - 1) / TB;   // 9375 blocks
    spmm_f8f8 <<<spmm_blocks, TB, 0, stream>>>(row_ptr, sorted, x0f8, E1f8);
    spmm_f8f16<<<spmm_blocks, TB, 0, stream>>>(row_ptr, sorted, E1f8, E2h);
    // 8. layer 3 (batch rows) + combine
    int final_blocks = (3 * BATCH * 16 + TB - 1) / TB; // 768 blocks
    final_kernel<<<final_blocks, TB, 0, stream>>>(
        row_ptr, sorted, user_emb, item_emb, x0f8, E2h, users, pos_items, neg_items, out);
}